// Round 4
// baseline (113.131 us; speedup 1.0000x reference)
//
#include <hip/hip_runtime.h>
#include <hip/hip_bf16.h>
#include <float.h>

// ---------------------------------------------------------------------------
// SCANCircuitV4C: output depends only on the root buffer; MLP inputs quantize
// to 2 used mod + 32 comb configs -> precompute tiny tables, then per-batch
// table lookup. R3: fused to TWO kernels. Kernel1 computes mod col-0 rows
// (configs 2,3 only), Gram matrix, and full comb attention rows (each comb
// block computes its own h2 from L2-resident cw2). Kernel2 decodes each tree
// and reduces against the attention table on the fly.
// ---------------------------------------------------------------------------

#define NNODE 16

// ws float offsets
#define MODCOL_OFF 0       // [4][48]  attn_mod[p,0]; only rows 2,3 written/read
#define G_OFF      192     // [8][8]   E @ E^T
#define ATT_OFF    256     // [32][48][96]  full comb attention rows
// total 256 + 147456 floats = 590 KB

__device__ __forceinline__ float gelu_exact(float x) {
    return 0.5f * x * (1.0f + erff(x * 0.70710678118654752f));
}

__device__ __forceinline__ float dot128(const float* __restrict__ w,
                                        const float* __restrict__ h) {
    const float4* w4 = (const float4*)w;
    float s = 0.f;
    #pragma unroll
    for (int i = 0; i < 32; ++i) {
        float4 v = w4[i];
        s += v.x * h[4 * i + 0] + v.y * h[4 * i + 1] +
             v.z * h[4 * i + 2] + v.w * h[4 * i + 3];
    }
    return s;
}

// Kernel 1: blocks 0..95   -> mod config (2+blk/48), row blk%48 -> col-0 attn
//           block  96      -> Gram matrix
//           blocks 97..1632-> comb (p = u>>5, c = u&31): own h2 + attn row
__global__ __launch_bounds__(128) void scan_tables(
    const float* __restrict__ E,
    const float* __restrict__ mw1, const float* __restrict__ mb1,
    const float* __restrict__ mw2, const float* __restrict__ mb2,
    const float* __restrict__ mw3, const float* __restrict__ mb3,
    const float* __restrict__ cw1, const float* __restrict__ cb1,
    const float* __restrict__ cw2, const float* __restrict__ cb2,
    const float* __restrict__ cw3, const float* __restrict__ cb3,
    float* __restrict__ ws)
{
    __shared__ float h1[128];
    __shared__ float h2s[128];
    __shared__ float lg[96];
    __shared__ float red[4];

    const int tid = threadIdx.x;
    const int blk = blockIdx.x;

    if (blk < 96) {
        const int mm = blk / 48, p = blk % 48;   // config m = 2 + mm (cnt=1)
        const float f0 = 1.0f / 48.0f;
        const float f1 = (mm == 0) ? 1.0f : 0.0f;
        const float f2 = (mm == 1) ? 1.0f : 0.0f;
        h1[tid] = gelu_exact(mw1[tid * 3 + 0] * f0 + mw1[tid * 3 + 1] * f1 +
                             mw1[tid * 3 + 2] * f2 + mb1[tid]);
        __syncthreads();
        h2s[tid] = gelu_exact(dot128(mw2 + tid * 128, h1) + mb2[tid]);
        __syncthreads();
        if (tid < 48)
            lg[tid] = dot128(mw3 + (p * 48 + tid) * 128, h2s) + mb3[p * 48 + tid];
        __syncthreads();
        if (tid == 0) {
            float mx = lg[0];
            for (int q = 1; q < 48; ++q) mx = fmaxf(mx, lg[q]);
            float s = 0.f;
            for (int q = 0; q < 48; ++q) s += expf(lg[q] - mx);
            ws[MODCOL_OFF + (2 + mm) * 48 + p] = expf(lg[0] - mx) / s;
        }
        return;
    }
    if (blk == 96) {
        if (tid < 64) {
            const int i = tid >> 3, a = tid & 7;
            float s = 0.f;
            #pragma unroll
            for (int d = 0; d < 32; ++d) s += E[i * 32 + d] * E[a * 32 + d];
            ws[G_OFF + tid] = s;
        }
        return;
    }

    // ---- comb block: p-major so 32 consecutive blocks share the cw3 p-slice
    const int u = blk - 97;
    const int p = u >> 5;
    const int c = u & 31;
    const int csub = c & 1;
    const int rc = (c >> 1) & 3;
    const int lc = (c >> 3) & 3;

    const float f0 = (float)lc / 48.0f;
    const float f1 = (float)rc / 48.0f;
    const float f2 = (csub == 0) ? 1.0f : 0.0f;
    const float f3 = (csub == 1) ? 1.0f : 0.0f;
    h1[tid] = gelu_exact(cw1[tid * 4 + 0] * f0 + cw1[tid * 4 + 1] * f1 +
                         cw1[tid * 4 + 2] * f2 + cw1[tid * 4 + 3] * f3 + cb1[tid]);
    __syncthreads();
    h2s[tid] = gelu_exact(dot128(cw2 + tid * 128, h1) + cb2[tid]);
    __syncthreads();

    // logits: 4 lanes per row, 3 passes of 32 rows (64B contiguous per quad)
    const int j = tid & 3;
    const int rbase = tid >> 2;
    const float4* h24 = (const float4*)h2s;
    #pragma unroll
    for (int o = 0; o < 3; ++o) {
        const int r = o * 32 + rbase;
        const float4* w4 = (const float4*)(cw3 + (p * 96 + r) * 128);
        float s = 0.f;
        #pragma unroll
        for (int i = 0; i < 8; ++i) {
            const int f4i = i * 4 + j;
            float4 w = w4[f4i];
            float4 h = h24[f4i];
            s += w.x * h.x + w.y * h.y + w.z * h.z + w.w * h.w;
        }
        s += __shfl_xor(s, 1);
        s += __shfl_xor(s, 2);
        if (j == 0) lg[r] = s;
    }
    __syncthreads();

    // softmax over 96 via shuffles (2 waves)
    const int wv = tid >> 6;
    float lv = (tid < 96) ? (lg[tid] + cb3[p * 96 + tid]) : -FLT_MAX;
    float m = lv;
    #pragma unroll
    for (int d = 32; d > 0; d >>= 1) m = fmaxf(m, __shfl_xor(m, d));
    if ((tid & 63) == 0) red[wv] = m;
    __syncthreads();
    const float mx = fmaxf(red[0], red[1]);

    float ev = (tid < 96) ? expf(lv - mx) : 0.f;
    float sum = ev;
    #pragma unroll
    for (int d = 32; d > 0; d >>= 1) sum += __shfl_xor(sum, d);
    if ((tid & 63) == 0) red[2 + wv] = sum;
    __syncthreads();
    const float inv = 1.0f / (red[2] + red[3]);

    if (tid < 96)
        ws[ATT_OFF + (c * 48 + p) * 96 + tid] = ev * inv;
}

// Kernel 2: per-batch decode + on-the-fly reduction against the attn table.
// side modes: 0=zero, 1=gather ws[base+p*stride], 2=prim-root (w[0]=1),
//             3=dot: sum_q ws[base+p*96+q] * modcol[2+msel][q]
__global__ __launch_bounds__(384) void scan_output(
    const int* __restrict__ cats, const int* __restrict__ subs,
    const int* __restrict__ mask, const int* __restrict__ cl,
    const int* __restrict__ cr,
    const float* __restrict__ ws,
    float* __restrict__ out)
{
    __shared__ int sc[NNODE], ss[NNODE], sm[NNODE], sl[NNODE], sr[NNODE];
    __shared__ int s_dec[11];
    __shared__ float s_G[64];
    __shared__ float s_mc[96];   // modcol rows 2,3
    __shared__ float s_w[96];    // per-row weights, L then R

    const int b = blockIdx.x;
    const int tid = threadIdx.x;
    if (tid < NNODE) {
        sc[tid] = cats[b * NNODE + tid];
        ss[tid] = subs[b * NNODE + tid];
        sm[tid] = mask[b * NNODE + tid];
        sl[tid] = cl[b * NNODE + tid];
        sr[tid] = cr[b * NNODE + tid];
    } else if (tid >= 96 && tid < 192) {
        s_mc[tid - 96] = ws[MODCOL_OFF + 96 + (tid - 96)];
    } else if (tid >= 192 && tid < 256) {
        s_G[tid - 192] = ws[G_OFF + tid - 192];
    }
    __syncthreads();

    if (tid == 0) {
        auto clampN  = [](int x) { return x < 0 ? 0 : (x > NNODE - 1 ? NNODE - 1 : x); };
        auto clamp01 = [](int x) { return x < 0 ? 0 : (x > 1 ? 1 : x); };
        auto clampA  = [](int x) { return x < 0 ? 0 : (x > 7 ? 7 : x); };
        auto PRIM = [&](int n) { return (sc[n] == 0) && (sm[n] != 0); };
        auto MODM = [&](int n) { return (sc[n] == 1) && (sm[n] != 0); };
        auto AID  = [&](int n) { return clampA(ss[n] + 1); };

        int modeL = 0, modeR = 0, baseL = 0, baseR = 0, strideL = 0, strideR = 0;
        int mselL = 0, mselR = 0, aidL = 0, aidR = 0, count0 = 0;
        const int  cat0 = sc[0];
        const bool msk0 = sm[0] != 0;
        const int  sub0 = clamp01(ss[0]);
        const int  cl0  = clampN(sl[0]);
        const int  cr0  = clampN(sr[0]);

        if (cat0 == 2 && msk0) {
            auto cnt2 = [&](int n) -> int {
                if (MODM(n)) {
                    int c1 = PRIM(clampN(sl[n])) ? 1 : 0;
                    int f  = clamp01(ss[n]) ? 3 : 2;
                    int v  = c1 * f;
                    return v > 48 ? 48 : v;
                }
                return PRIM(n) ? 1 : 0;
            };
            const int l = cl0, r = cr0;
            const int lcc = cnt2(l), rcc = cnt2(r);
            const int cidx = (lcc * 4 + rcc) * 2 + sub0;
            const int abase = ATT_OFF + cidx * 4608;   // 48*96
            count0 = lcc + rcc; if (count0 > 48) count0 = 48;
            if (MODM(l)) {
                const int g = clampN(sl[l]);
                if (PRIM(g)) {   // mod child with nonzero source
                    modeL = 3; aidL = AID(g); mselL = clamp01(ss[l]);
                    baseL = abase;            // + p*96 + q
                }
            } else if (PRIM(l)) {
                modeL = 1; aidL = AID(l);
                baseL = abase; strideL = 96;  // att[p][0]
            }
            if (MODM(r)) {
                const int g = clampN(sl[r]);
                if (PRIM(g)) {
                    modeR = 3; aidR = AID(g); mselR = clamp01(ss[r]);
                    baseR = abase + 48;
                }
            } else if (PRIM(r)) {
                modeR = 1; aidR = AID(r);
                baseR = abase + 48; strideR = 96;  // att[p][48]
            }
        } else if (cat0 == 1 && msk0) {
            const int ch = cl0;
            const int c1 = PRIM(ch) ? 1 : 0;
            count0 = c1 * (sub0 ? 3 : 2); if (count0 > 48) count0 = 48;
            if (c1) {
                modeL = 1; aidL = AID(ch);
                baseL = MODCOL_OFF + (2 + sub0) * 48; strideL = 1;
            }
        } else if (cat0 == 0 && msk0) {
            modeL = 2; aidL = AID(0); count0 = 1;
        }
        s_dec[0] = modeL;  s_dec[1] = modeR;
        s_dec[2] = baseL;  s_dec[3] = baseR;
        s_dec[4] = strideL; s_dec[5] = strideR;
        s_dec[6] = mselL;  s_dec[7] = mselR;
        s_dec[8] = aidL;   s_dec[9] = aidR;
        s_dec[10] = count0;
    }
    __syncthreads();

    if (tid < 96) {
        const int side = tid / 48;
        const int p = tid - side * 48;
        const int mode = s_dec[0 + side];
        const int base = s_dec[2 + side];
        float w = 0.f;
        if (mode == 1) {
            w = ws[base + p * s_dec[4 + side]];
        } else if (mode == 2) {
            w = (p == 0) ? 1.0f : 0.0f;
        } else if (mode == 3) {
            const float4* ar = (const float4*)(ws + base + p * 96);
            const float4* mr = (const float4*)(s_mc + s_dec[6 + side] * 48);
            float s = 0.f;
            #pragma unroll
            for (int q = 0; q < 12; ++q) {
                float4 a4 = ar[q], m4 = mr[q];
                s += a4.x * m4.x + a4.y * m4.y + a4.z * m4.z + a4.w * m4.w;
            }
            w = s;
        }
        s_w[tid] = w;
    }
    __syncthreads();

    const int p = tid >> 3, a = tid & 7;
    float v = s_w[p]      * s_G[s_dec[8] * 8 + a]
            + s_w[48 + p] * s_G[s_dec[9] * 8 + a];
    if (a == 0 && p >= s_dec[10]) v += 8.0f;
    out[b * 384 + tid] = v;
}

extern "C" void kernel_launch(void* const* d_in, const int* in_sizes, int n_in,
                              void* d_out, int out_size, void* d_ws, size_t ws_size,
                              hipStream_t stream) {
    const int* cats = (const int*)d_in[0];
    const int* subs = (const int*)d_in[1];
    const int* mask = (const int*)d_in[2];
    const int* cl   = (const int*)d_in[3];
    const int* cr   = (const int*)d_in[4];
    const float* E   = (const float*)d_in[5];
    const float* mw1 = (const float*)d_in[6];
    const float* mb1 = (const float*)d_in[7];
    const float* mw2 = (const float*)d_in[8];
    const float* mb2 = (const float*)d_in[9];
    const float* mw3 = (const float*)d_in[10];
    const float* mb3 = (const float*)d_in[11];
    const float* cw1 = (const float*)d_in[12];
    const float* cb1 = (const float*)d_in[13];
    const float* cw2 = (const float*)d_in[14];
    const float* cb2 = (const float*)d_in[15];
    const float* cw3 = (const float*)d_in[16];
    const float* cb3 = (const float*)d_in[17];
    float* ws  = (float*)d_ws;
    float* out = (float*)d_out;
    const int B = in_sizes[0] / NNODE;

    scan_tables<<<97 + 48 * 32, 128, 0, stream>>>(E, mw1, mb1, mw2, mb2, mw3, mb3,
                                                  cw1, cb1, cw2, cb2, cw3, cb3, ws);
    scan_output<<<B, 384, 0, stream>>>(cats, subs, mask, cl, cr, ws, out);
}

// Round 6
// 105.364 us; speedup vs baseline: 1.0737x; 1.0737x over previous
//
#include <hip/hip_runtime.h>
#include <hip/hip_bf16.h>
#include <float.h>

// ---------------------------------------------------------------------------
// SCANCircuitV4C: output depends only on the root buffer; MLP inputs quantize
// to 2 used mod + 32 comb configs -> precompute tiny tables, then per-batch
// table lookup. R5 = R3 structure (fastest) with: mod configs {2,3} only,
// wave-parallel softmax in kernel A, halved mod-dot table in kernel B.
// (Resubmit of R5 — prior round hit GPUAcquisitionTimeout, never measured.)
// ---------------------------------------------------------------------------

#define NNODE 16

// ws float offsets
#define MODCOL_OFF 0       // [4][48]   attn_mod[p,0]; only rows 2,3 written/read
#define G_OFF      192     // [8][8]    E @ E^T
#define C0_OFF     256     // [32][48]  attn_comb[p,0]
#define C48_OFF    1792    // [32][48]  attn_comb[p,48]
#define DOTL_OFF   3328    // [32][2][48] sum_q attnC[p,q]   * modcol0[2+s][q]
#define DOTR_OFF   6400    // [32][2][48] sum_q attnC[p,48+q]* modcol0[2+s][q]
#define H2_OFF     9472    // [32][128] comb h2 per config
// total 13568 floats = 54272 bytes

__device__ __forceinline__ float gelu_exact(float x) {
    return 0.5f * x * (1.0f + erff(x * 0.70710678118654752f));
}

__device__ __forceinline__ float dot128(const float* __restrict__ w,
                                        const float* __restrict__ h) {
    const float4* w4 = (const float4*)w;
    float s = 0.f;
    #pragma unroll
    for (int i = 0; i < 32; ++i) {
        float4 v = w4[i];
        s += v.x * h[4 * i + 0] + v.y * h[4 * i + 1] +
             v.z * h[4 * i + 2] + v.w * h[4 * i + 3];
    }
    return s;
}

// Kernel A: blocks 0..95  -> mod config (2 + blk/48), row blk%48 -> col-0 attn
//           block  96     -> Gram matrix
//           blocks 97..128-> comb h2 per config (blk-97)
__global__ __launch_bounds__(128) void scan_tables_a(
    const float* __restrict__ E,
    const float* __restrict__ mw1, const float* __restrict__ mb1,
    const float* __restrict__ mw2, const float* __restrict__ mb2,
    const float* __restrict__ mw3, const float* __restrict__ mb3,
    const float* __restrict__ cw1, const float* __restrict__ cb1,
    const float* __restrict__ cw2, const float* __restrict__ cb2,
    float* __restrict__ ws)
{
    __shared__ float h1[128];
    __shared__ float h2s[128];
    __shared__ float lg[48];

    const int tid = threadIdx.x;
    const int blk = blockIdx.x;

    if (blk < 96) {
        const int mm = blk / 48, p = blk % 48;   // config m = 2 + mm (cnt = 1)
        const float f0 = 1.0f / 48.0f;
        const float f1 = (mm == 0) ? 1.0f : 0.0f;
        const float f2 = (mm == 1) ? 1.0f : 0.0f;
        h1[tid] = gelu_exact(mw1[tid * 3 + 0] * f0 + mw1[tid * 3 + 1] * f1 +
                             mw1[tid * 3 + 2] * f2 + mb1[tid]);
        __syncthreads();
        h2s[tid] = gelu_exact(dot128(mw2 + tid * 128, h1) + mb2[tid]);
        __syncthreads();
        if (tid < 48)
            lg[tid] = dot128(mw3 + (p * 48 + tid) * 128, h2s) + mb3[p * 48 + tid];
        __syncthreads();
        if (tid < 64) {  // wave 0: parallel softmax over 48
            float lv = (tid < 48) ? lg[tid] : -FLT_MAX;
            float mx = lv;
            #pragma unroll
            for (int d = 32; d > 0; d >>= 1) mx = fmaxf(mx, __shfl_xor(mx, d));
            float ev = (tid < 48) ? expf(lv - mx) : 0.f;
            float sm = ev;
            #pragma unroll
            for (int d = 32; d > 0; d >>= 1) sm += __shfl_xor(sm, d);
            if (tid == 0)
                ws[MODCOL_OFF + (2 + mm) * 48 + p] = ev / sm;  // lane0 ev = exp(lg[0]-mx)
        }
        return;
    }
    if (blk == 96) {
        if (tid < 64) {
            const int i = tid >> 3, a = tid & 7;
            float s = 0.f;
            #pragma unroll
            for (int d = 0; d < 32; ++d) s += E[i * 32 + d] * E[a * 32 + d];
            ws[G_OFF + tid] = s;
        }
        return;
    }
    {
        const int c = blk - 97;
        const int csub = c & 1;
        const int rc = (c >> 1) & 3;
        const int lc = (c >> 3) & 3;
        const float f0 = (float)lc / 48.0f;
        const float f1 = (float)rc / 48.0f;
        const float f2 = (csub == 0) ? 1.0f : 0.0f;
        const float f3 = (csub == 1) ? 1.0f : 0.0f;
        h1[tid] = gelu_exact(cw1[tid * 4 + 0] * f0 + cw1[tid * 4 + 1] * f1 +
                             cw1[tid * 4 + 2] * f2 + cw1[tid * 4 + 3] * f3 + cb1[tid]);
        __syncthreads();
        ws[H2_OFF + c * 128 + tid] =
            gelu_exact(dot128(cw2 + tid * 128, h1) + cb2[tid]);
    }
}

// Kernel B: one block per (row p, comb config c), blockIdx = p*32 + c so that
// 32 consecutive blocks share the same 48KB cw3 slice (L2 locality).
// Quad-coalesced logit dots + shuffle softmax; mod dots only for m in {2,3}.
__global__ __launch_bounds__(128, 4) void scan_tables_b(
    const float* __restrict__ cw3, const float* __restrict__ cb3,
    float* __restrict__ ws)
{
    __shared__ float h2s[128];
    __shared__ float mc[96];    // mod columns rows 2,3
    __shared__ float lg[96];    // raw logits
    __shared__ float pr[96];    // exp(logit - mx)
    __shared__ float red[4];

    const int tid = threadIdx.x;
    const int p = blockIdx.x >> 5;
    const int c = blockIdx.x & 31;

    h2s[tid] = ws[H2_OFF + c * 128 + tid];
    if (tid < 96) mc[tid] = ws[MODCOL_OFF + 96 + tid];
    __syncthreads();

    // logits: 4 lanes per row, 3 passes of 32 rows (64B contiguous per quad)
    const int j = tid & 3;
    const int rbase = tid >> 2;
    const float4* h24 = (const float4*)h2s;
    #pragma unroll
    for (int o = 0; o < 3; ++o) {
        const int r = o * 32 + rbase;
        const float4* w4 = (const float4*)(cw3 + (p * 96 + r) * 128);
        float s = 0.f;
        #pragma unroll
        for (int i = 0; i < 8; ++i) {
            const int f4i = i * 4 + j;
            float4 w = w4[f4i];
            float4 h = h24[f4i];
            s += w.x * h.x + w.y * h.y + w.z * h.z + w.w * h.w;
        }
        s += __shfl_xor(s, 1);
        s += __shfl_xor(s, 2);
        if (j == 0) lg[r] = s;
    }
    __syncthreads();

    // softmax over 96 via shuffles (2 waves)
    const int wv = tid >> 6;
    float lv = (tid < 96) ? (lg[tid] + cb3[p * 96 + tid]) : -FLT_MAX;
    float m = lv;
    #pragma unroll
    for (int d = 32; d > 0; d >>= 1) m = fmaxf(m, __shfl_xor(m, d));
    if ((tid & 63) == 0) red[wv] = m;
    __syncthreads();
    const float mx = fmaxf(red[0], red[1]);

    float ev = (tid < 96) ? expf(lv - mx) : 0.f;
    if (tid < 96) pr[tid] = ev;
    float sum = ev;
    #pragma unroll
    for (int d = 32; d > 0; d >>= 1) sum += __shfl_xor(sum, d);
    if ((tid & 63) == 0) red[2 + wv] = sum;
    __syncthreads();
    const float inv = 1.0f / (red[2] + red[3]);

    if (tid == 0) {
        ws[C0_OFF + c * 48 + p]  = pr[0]  * inv;
        ws[C48_OFF + c * 48 + p] = pr[48] * inv;
    }
    if (tid < 4) {
        const int mm = tid & 1;          // msub (config 2+mm)
        const int side = tid >> 1;       // 0 = L, 1 = R
        const float* q0 = pr + side * 48;
        const float* mr = mc + mm * 48;
        float s = 0.f;
        #pragma unroll
        for (int q = 0; q < 48; ++q) s += q0[q] * mr[q];
        const int off = (side == 0 ? DOTL_OFF : DOTR_OFF) + (c * 2 + mm) * 48 + p;
        ws[off] = s * inv;
    }
}

__global__ __launch_bounds__(384) void scan_output(
    const int* __restrict__ cats, const int* __restrict__ subs,
    const int* __restrict__ mask, const int* __restrict__ cl,
    const int* __restrict__ cr,
    const float* __restrict__ ws,
    float* __restrict__ out)
{
    __shared__ int sc[NNODE], ss[NNODE], sm[NNODE], sl[NNODE], sr[NNODE];
    __shared__ int s_dec[7];  // modeL, modeR, offL, offR, aidL, aidR, count0
    __shared__ float s_G[64];

    const int b = blockIdx.x;
    const int tid = threadIdx.x;
    if (tid < NNODE) {
        sc[tid] = cats[b * NNODE + tid];
        ss[tid] = subs[b * NNODE + tid];
        sm[tid] = mask[b * NNODE + tid];
        sl[tid] = cl[b * NNODE + tid];
        sr[tid] = cr[b * NNODE + tid];
    } else if (tid >= 64 && tid < 128) {
        s_G[tid - 64] = ws[G_OFF + tid - 64];
    }
    __syncthreads();

    if (tid == 0) {
        auto clampN  = [](int x) { return x < 0 ? 0 : (x > NNODE - 1 ? NNODE - 1 : x); };
        auto clamp01 = [](int x) { return x < 0 ? 0 : (x > 1 ? 1 : x); };
        auto clampA  = [](int x) { return x < 0 ? 0 : (x > 7 ? 7 : x); };
        auto PRIM = [&](int n) { return (sc[n] == 0) && (sm[n] != 0); };
        auto MODM = [&](int n) { return (sc[n] == 1) && (sm[n] != 0); };
        auto AID  = [&](int n) { return clampA(ss[n] + 1); };

        int modeL = 0, modeR = 0, offL = 0, offR = 0, aidL = 0, aidR = 0, count0 = 0;
        const int  cat0 = sc[0];
        const bool msk0 = sm[0] != 0;
        const int  sub0 = clamp01(ss[0]);
        const int  cl0  = clampN(sl[0]);
        const int  cr0  = clampN(sr[0]);

        if (cat0 == 2 && msk0) {
            // comb root: children come from post-mod (stage-2) buffers/counts
            auto cnt2 = [&](int n) -> int {
                if (MODM(n)) {
                    int c1 = PRIM(clampN(sl[n])) ? 1 : 0;
                    int f  = clamp01(ss[n]) ? 3 : 2;
                    int v  = c1 * f;
                    return v > 48 ? 48 : v;
                }
                return PRIM(n) ? 1 : 0;
            };
            const int l = cl0, r = cr0;
            const int lcc = cnt2(l), rcc = cnt2(r);
            const int cidx = (lcc * 4 + rcc) * 2 + sub0;
            count0 = lcc + rcc; if (count0 > 48) count0 = 48;
            if (MODM(l)) {
                const int g = clampN(sl[l]);
                if (PRIM(g)) {  // mod child with nonzero source (child_cnt==1)
                    modeL = 1; aidL = AID(g);
                    offL = DOTL_OFF + (cidx * 2 + clamp01(ss[l])) * 48;
                }
            } else if (PRIM(l)) {
                modeL = 1; aidL = AID(l);
                offL = C0_OFF + cidx * 48;
            }
            if (MODM(r)) {
                const int g = clampN(sl[r]);
                if (PRIM(g)) {
                    modeR = 1; aidR = AID(g);
                    offR = DOTR_OFF + (cidx * 2 + clamp01(ss[r])) * 48;
                }
            } else if (PRIM(r)) {
                modeR = 1; aidR = AID(r);
                offR = C48_OFF + cidx * 48;
            }
        } else if (cat0 == 1 && msk0) {
            // mod root
            const int ch = cl0;
            const int c1 = PRIM(ch) ? 1 : 0;
            count0 = c1 * (sub0 ? 3 : 2); if (count0 > 48) count0 = 48;
            if (c1) {
                modeL = 1; aidL = AID(ch);
                offL = MODCOL_OFF + (2 + sub0) * 48;
            }
        } else if (cat0 == 0 && msk0) {
            // prim root: only row p==0 nonzero
            modeL = 2; aidL = AID(0); count0 = 1;
        }
        s_dec[0] = modeL; s_dec[1] = modeR; s_dec[2] = offL; s_dec[3] = offR;
        s_dec[4] = aidL;  s_dec[5] = aidR;  s_dec[6] = count0;
    }
    __syncthreads();

    const int p = tid >> 3, a = tid & 7;
    const int modeL = s_dec[0], modeR = s_dec[1];
    float v = 0.f;
    if (modeL == 1)       v += ws[s_dec[2] + p] * s_G[s_dec[4] * 8 + a];
    else if (modeL == 2)  { if (p == 0) v = s_G[s_dec[4] * 8 + a]; }
    if (modeR == 1)       v += ws[s_dec[3] + p] * s_G[s_dec[5] * 8 + a];
    if (a == 0 && p >= s_dec[6]) v += 8.0f;
    out[b * 384 + tid] = v;
}

extern "C" void kernel_launch(void* const* d_in, const int* in_sizes, int n_in,
                              void* d_out, int out_size, void* d_ws, size_t ws_size,
                              hipStream_t stream) {
    const int* cats = (const int*)d_in[0];
    const int* subs = (const int*)d_in[1];
    const int* mask = (const int*)d_in[2];
    const int* cl   = (const int*)d_in[3];
    const int* cr   = (const int*)d_in[4];
    const float* E   = (const float*)d_in[5];
    const float* mw1 = (const float*)d_in[6];
    const float* mb1 = (const float*)d_in[7];
    const float* mw2 = (const float*)d_in[8];
    const float* mb2 = (const float*)d_in[9];
    const float* mw3 = (const float*)d_in[10];
    const float* mb3 = (const float*)d_in[11];
    const float* cw1 = (const float*)d_in[12];
    const float* cb1 = (const float*)d_in[13];
    const float* cw2 = (const float*)d_in[14];
    const float* cb2 = (const float*)d_in[15];
    const float* cw3 = (const float*)d_in[16];
    const float* cb3 = (const float*)d_in[17];
    float* ws  = (float*)d_ws;
    float* out = (float*)d_out;
    const int B = in_sizes[0] / NNODE;

    scan_tables_a<<<129, 128, 0, stream>>>(E, mw1, mb1, mw2, mb2, mw3, mb3,
                                           cw1, cb1, cw2, cb2, ws);
    scan_tables_b<<<48 * 32, 128, 0, stream>>>(cw3, cb3, ws);
    scan_output<<<B, 384, 0, stream>>>(cats, subs, mask, cl, cr, ws, out);
}